// Round 1
// baseline (1203.991 us; speedup 1.0000x reference)
//
#include <hip/hip_runtime.h>

using u16 = unsigned short;
using u32 = unsigned int;

typedef __attribute__((ext_vector_type(8))) short bf16x8;
typedef __attribute__((ext_vector_type(4))) float f32x4;

// ---------- fp32 <-> bf16 hi/lo split helpers ----------
__device__ __forceinline__ u16 f2bf(float f) {
  u32 u = __float_as_uint(f);
  u += 0x7fffu + ((u >> 16) & 1u);   // RNE
  return (u16)(u >> 16);
}
__device__ __forceinline__ float bf2f(u16 h) { return __uint_as_float(((u32)h) << 16); }

// async global->LDS, 16B per lane; LDS dest is wave-uniform base + lane*16
__device__ __forceinline__ void gld16(const u16* g, u16* s) {
  __builtin_amdgcn_global_load_lds((const __attribute__((address_space(1))) u32*)g,
                                   (__attribute__((address_space(3))) u32*)s, 16, 0, 0);
}

struct EpParams {
  const float* bias;
  const float* bnsc;
  const float* bnsh;
  u16* dhi; u16* dlo; int dstride;
  float* f32a; float* f32b; int f32stride;
  const float* nscale; const float* escale;
};

// ---------------------------------------------------------------------------
// Split-bf16 MFMA GEMM: C[M,N] = A[M,K] * B[K,N] (+ epilogue)
// A given as hi/lo bf16 row-major [M,K] (row stride lda).
// B given as hi/lo bf16 TRANSPOSED [Npad,K] (row stride K), zero-padded rows.
// 128x128 tile, BK=32, 4 waves (2x2), each wave 64x64 = 4x4 frags of 16x16.
// EP: 0=BN(ReLU)+hilo store  1=mu/lv  2=tanh+hilo  3=fp32+bias  4=dec2 scaled
// ---------------------------------------------------------------------------
template<int EP>
__global__ __launch_bounds__(256, 2) void gemm_k(
    const u16* __restrict__ Ah, const u16* __restrict__ Al, int lda,
    const u16* __restrict__ Bh, const u16* __restrict__ Bl,
    int K, int N, EpParams p)
{
  __shared__ __align__(16) u16 sAh[4096], sAl[4096], sBh[4096], sBl[4096];
  const int t = threadIdx.x;
  const int lane = t & 63, wid = t >> 6;
  const int tm = blockIdx.x, tn = blockIdx.y;

  // staging: thread t loads 8 bf16 at (row=t>>2, col=(t&3)*8); round2 = +64 rows
  const int srow = t >> 2, scol = (t & 3) << 3;
  const u16* pAh = Ah + (size_t)(tm * 128 + srow) * (size_t)lda + scol;
  const u16* pAl = Al + (size_t)(tm * 128 + srow) * (size_t)lda + scol;
  const u16* pBh = Bh + (size_t)(tn * 128 + srow) * (size_t)K + scol;
  const u16* pBl = Bl + (size_t)(tn * 128 + srow) * (size_t)K + scol;
  const size_t aStep = (size_t)64 * (size_t)lda;
  const size_t bStep = (size_t)64 * (size_t)K;
  u16* const dst0 = (u16*)nullptr;  (void)dst0;

  f32x4 acc[4][4];
#pragma unroll
  for (int m = 0; m < 4; m++)
#pragma unroll
    for (int n = 0; n < 4; n++) acc[m][n] = f32x4{0.f, 0.f, 0.f, 0.f};

  const int fr = lane & 15, fg = lane >> 4;
  const int wm = wid >> 1, wn = wid & 1;
  const int arow = wm * 64 + fr;     // + fm*16
  const int brow = wn * 64 + fr;     // + fn*16

  for (int kk = 0; kk < K; kk += 32) {
    gld16(pAh + kk,          sAh + wid * 512);
    gld16(pAh + aStep + kk,  sAh + 2048 + wid * 512);
    gld16(pAl + kk,          sAl + wid * 512);
    gld16(pAl + aStep + kk,  sAl + 2048 + wid * 512);
    gld16(pBh + kk,          sBh + wid * 512);
    gld16(pBh + bStep + kk,  sBh + 2048 + wid * 512);
    gld16(pBl + kk,          sBl + wid * 512);
    gld16(pBl + bStep + kk,  sBl + 2048 + wid * 512);
    __syncthreads();

    bf16x8 a_h[4], a_l[4], b_h[4], b_l[4];
#pragma unroll
    for (int f = 0; f < 4; f++) {
      a_h[f] = *(const bf16x8*)&sAh[(arow + f * 16) * 32 + fg * 8];
      a_l[f] = *(const bf16x8*)&sAl[(arow + f * 16) * 32 + fg * 8];
      b_h[f] = *(const bf16x8*)&sBh[(brow + f * 16) * 32 + fg * 8];
      b_l[f] = *(const bf16x8*)&sBl[(brow + f * 16) * 32 + fg * 8];
    }
#pragma unroll
    for (int m = 0; m < 4; m++)
#pragma unroll
      for (int n = 0; n < 4; n++) {
        acc[m][n] = __builtin_amdgcn_mfma_f32_16x16x32_bf16(a_h[m], b_l[n], acc[m][n], 0, 0, 0);
        acc[m][n] = __builtin_amdgcn_mfma_f32_16x16x32_bf16(a_l[m], b_h[n], acc[m][n], 0, 0, 0);
        acc[m][n] = __builtin_amdgcn_mfma_f32_16x16x32_bf16(a_h[m], b_h[n], acc[m][n], 0, 0, 0);
      }
    __syncthreads();
  }

  // epilogue: C/D layout col=lane&15, row=4*(lane>>4)+reg  [m89-verified]
  const int rowb = tm * 128 + wm * 64;
  const int colb = tn * 128 + wn * 64;
#pragma unroll
  for (int n = 0; n < 4; n++) {
    const int col = colb + n * 16 + fr;
#pragma unroll
    for (int m = 0; m < 4; m++) {
#pragma unroll
      for (int r = 0; r < 4; r++) {
        const int row = rowb + m * 16 + fg * 4 + r;
        float val = acc[m][n][r];
        if constexpr (EP == 0) {          // bias -> relu -> bn -> hilo store
          val += p.bias[col];
          val = fmaxf(val, 0.f);
          val = val * p.bnsc[col] + p.bnsh[col];
          u16 h = f2bf(val);
          p.dhi[(size_t)row * p.dstride + col] = h;
          p.dlo[(size_t)row * p.dstride + col] = f2bf(val - bf2f(h));
        } else if constexpr (EP == 1) {   // mu (fp32 + hilo z) | logvar (fp32)
          val += p.bias[col];
          if (col < 256) {
            p.f32a[(size_t)row * 256 + col] = val;
            u16 h = f2bf(val);
            p.dhi[(size_t)row * 256 + col] = h;
            p.dlo[(size_t)row * 256 + col] = f2bf(val - bf2f(h));
          } else {
            p.f32b[(size_t)row * 256 + (col - 256)] = val;
          }
        } else if constexpr (EP == 2) {   // tanh -> hilo store (dhi pre-offset)
          val = tanhf(val + p.bias[col]);
          u16 h = f2bf(val);
          p.dhi[(size_t)row * p.dstride + col] = h;
          p.dlo[(size_t)row * p.dstride + col] = f2bf(val - bf2f(h));
        } else if constexpr (EP == 3) {   // fp32 logits
          if (col < N) p.f32a[(size_t)row * p.f32stride + col] = val + p.bias[col];
        } else {                          // EP==4: dec2 -> scaled edge/node out
          if (col < N) {
            val += p.bias[col];
            if (col < 900) {
              int rr = col / 30, cc = col - rr * 30;
              float s = 1.f;
              if (rr >= 20 && cc >= 20 && rr <= cc) {
                int i0 = rr - 20, j0 = cc - 20;
                int k = i0 * 10 - ((i0 * (i0 - 1)) >> 1) + (j0 - i0);
                s = p.escale[(size_t)row * 55 + k];
              }
              p.f32a[(size_t)row * 900 + col] = val * s;
            } else {
              int tc = col - 900, rr = tc >> 6;
              float s = (rr >= 20) ? p.nscale[(size_t)row * 10 + (rr - 20)] : 1.f;
              p.f32b[(size_t)row * 1920 + tc] = val * s;
            }
          }
        }
      }
    }
  }
}

// ---------- elementwise fp32 -> (hi,lo) bf16, float4-vectorized ----------
__global__ void conv_act(const float* __restrict__ s, u16* __restrict__ h,
                         u16* __restrict__ l, int n4) {
  int i = blockIdx.x * blockDim.x + threadIdx.x;
  if (i >= n4) return;
  float4 v = ((const float4*)s)[i];
  ushort4 hh, ll;
  hh.x = f2bf(v.x); ll.x = f2bf(v.x - bf2f(hh.x));
  hh.y = f2bf(v.y); ll.y = f2bf(v.y - bf2f(hh.y));
  hh.z = f2bf(v.z); ll.z = f2bf(v.z - bf2f(hh.z));
  hh.w = f2bf(v.w); ll.w = f2bf(v.w - bf2f(hh.w));
  ((ushort4*)h)[i] = hh;
  ((ushort4*)l)[i] = ll;
}

// ---------- W[K,N] fp32 -> Wt hi/lo [.,K] transposed, zero-pad n>=N ----------
__global__ void conv_wT(const float* __restrict__ W, u16* __restrict__ Th,
                        u16* __restrict__ Tl, int K, int N) {
  __shared__ float tile[32][33];
  int k0 = blockIdx.x * 32, n0 = blockIdx.y * 32;
  int tx = threadIdx.x, ty = threadIdx.y;
#pragma unroll
  for (int i = ty; i < 32; i += 8) {
    int n = n0 + tx;
    tile[i][tx] = (n < N) ? W[(size_t)(k0 + i) * N + n] : 0.f;
  }
  __syncthreads();
#pragma unroll
  for (int i = ty; i < 32; i += 8) {
    int n = n0 + i, k = k0 + tx;
    float v = tile[tx][i];
    u16 h = f2bf(v);
    Th[(size_t)n * K + k] = h;
    Tl[(size_t)n * K + k] = f2bf(v - bf2f(h));
  }
}

// ---------- block-diag [Wa(512xNa); Wb(512xNb)] -> Wt hi/lo [128,1024] ----------
__global__ void conv_w2bd(const float* __restrict__ Wa, int Na,
                          const float* __restrict__ Wb, int Nb,
                          u16* __restrict__ Th, u16* __restrict__ Tl) {
  int idx = blockIdx.x * blockDim.x + threadIdx.x;
  if (idx >= 128 * 1024) return;
  int n = idx >> 10, k = idx & 1023;
  float v = 0.f;
  if (n < Na) { if (k < 512) v = Wa[(size_t)k * Na + n]; }
  else if (n < Na + Nb) { if (k >= 512) v = Wb[(size_t)(k - 512) * Nb + (n - Na)]; }
  u16 h = f2bf(v);
  Th[idx] = h;
  Tl[idx] = f2bf(v - bf2f(h));
}

// ---------- fold BN into scale/shift ----------
__global__ void bn_prep(const float* g, const float* b, const float* m,
                        const float* v, float* sc, float* sh, int n) {
  int i = blockIdx.x * blockDim.x + threadIdx.x;
  if (i < n) {
    float s = g[i] * rsqrtf(v[i] + 1e-5f);
    sc[i] = s;
    sh[i] = b[i] - m[i] * s;
  }
}

// ---------- combined double softmax -> per-batch scales ----------
// logits_opt[b,65]: 0-9 onw, 10-64 oew ; logits_log[b,90]: 0-11 lnw, 12-89 lew
__global__ void softmax_combine(const float* __restrict__ lo, const float* __restrict__ ll,
                                float* __restrict__ nsc, float* __restrict__ esc) {
  int b = blockIdx.x * blockDim.x + threadIdx.x;
  if (b >= 8192) return;
  const float* po = lo + (size_t)b * 65;
  const float* pl = ll + (size_t)b * 90;
  // nodes: softmax(po[0:10]) * softmax(pl[0:12])[0:10]
  float mo = po[0];
  for (int i = 1; i < 10; i++) mo = fmaxf(mo, po[i]);
  float so = 0.f;
  for (int i = 0; i < 10; i++) so += expf(po[i] - mo);
  float ml = pl[0];
  for (int i = 1; i < 12; i++) ml = fmaxf(ml, pl[i]);
  float sl = 0.f;
  for (int i = 0; i < 12; i++) sl += expf(pl[i] - ml);
  float invn = 1.f / (so * sl);
  for (int i = 0; i < 10; i++)
    nsc[(size_t)b * 10 + i] = expf(po[i] - mo) * expf(pl[i] - ml) * invn;
  // edges: softmax(po[10:65]) * softmax(pl[12:90])[0:55]
  const float* qo = po + 10;
  const float* ql = pl + 12;
  float meo = qo[0];
  for (int i = 1; i < 55; i++) meo = fmaxf(meo, qo[i]);
  float seo = 0.f;
  for (int i = 0; i < 55; i++) seo += expf(qo[i] - meo);
  float mel = ql[0];
  for (int i = 1; i < 78; i++) mel = fmaxf(mel, ql[i]);
  float sel = 0.f;
  for (int i = 0; i < 78; i++) sel += expf(ql[i] - mel);
  float inve = 1.f / (seo * sel);
  for (int k = 0; k < 55; k++)
    esc[(size_t)b * 55 + k] = expf(qo[k] - meo) * expf(ql[k] - mel) * inve;
}

// ---------------------------------------------------------------------------
extern "C" void kernel_launch(void* const* d_in, const int* in_sizes, int n_in,
                              void* d_out, int out_size, void* d_ws, size_t ws_size,
                              hipStream_t stream) {
  const float* x       = (const float*)d_in[0];
  const float* optical = (const float*)d_in[1];
  const float* logx    = (const float*)d_in[2];
  const float* enc_W   = (const float*)d_in[3];
  const float* enc_b   = (const float*)d_in[4];
  const float* bn1_g   = (const float*)d_in[5];
  const float* bn1_b   = (const float*)d_in[6];
  const float* bn1_m   = (const float*)d_in[7];
  const float* bn1_v   = (const float*)d_in[8];
  const float* mu_W    = (const float*)d_in[9];
  const float* mu_b    = (const float*)d_in[10];
  const float* lv_W    = (const float*)d_in[11];
  const float* lv_b    = (const float*)d_in[12];
  const float* dec_W1  = (const float*)d_in[13];
  const float* dec_b1  = (const float*)d_in[14];
  const float* bn2_g   = (const float*)d_in[15];
  const float* bn2_b   = (const float*)d_in[16];
  const float* bn2_m   = (const float*)d_in[17];
  const float* bn2_v   = (const float*)d_in[18];
  const float* dec_W2  = (const float*)d_in[19];
  const float* dec_b2  = (const float*)d_in[20];
  const float* on_W1   = (const float*)d_in[21];
  const float* on_b1   = (const float*)d_in[22];
  const float* on_W2   = (const float*)d_in[23];
  const float* on_b2   = (const float*)d_in[24];
  const float* oe_W1   = (const float*)d_in[25];
  const float* oe_b1   = (const float*)d_in[26];
  const float* oe_W2   = (const float*)d_in[27];
  const float* oe_b2   = (const float*)d_in[28];
  const float* ln_W1   = (const float*)d_in[29];
  const float* ln_b1   = (const float*)d_in[30];
  const float* ln_W2   = (const float*)d_in[31];
  const float* ln_b2   = (const float*)d_in[32];
  const float* le_W1   = (const float*)d_in[33];
  const float* le_b1   = (const float*)d_in[34];
  const float* le_W2   = (const float*)d_in[35];
  const float* le_b2   = (const float*)d_in[36];

  const int B = 8192;
  float* out_edge = (float*)d_out;
  float* out_node = out_edge + (size_t)B * 900;
  float* out_mu   = out_node + (size_t)B * 1920;
  float* out_lv   = out_mu + (size_t)B * 256;

  // ---- workspace carve (~232 MB) ----
  char* base = (char*)d_ws;
  size_t off = 0;
  auto takeB = [&](size_t elems) -> u16* {
    u16* p = (u16*)(base + off);
    off = (off + elems * 2 + 255) & ~(size_t)255;
    return p;
  };
  auto takeF = [&](size_t elems) -> float* {
    float* p = (float*)(base + off);
    off = (off + elems * 4 + 255) & ~(size_t)255;
    return p;
  };
  u16* wEncH  = takeB(2048 * 1024);  u16* wEncL  = takeB(2048 * 1024);
  u16* wMulvH = takeB(512 * 2048);   u16* wMulvL = takeB(512 * 2048);
  u16* wDec1H = takeB(2048 * 256);   u16* wDec1L = takeB(2048 * 256);
  u16* wDec2H = takeB(2944 * 2048);  u16* wDec2L = takeB(2944 * 2048);
  u16* wO1H   = takeB(1024 * 1024);  u16* wO1L   = takeB(1024 * 1024);
  u16* wL1H   = takeB(1024 * 1024);  u16* wL1L   = takeB(1024 * 1024);
  u16* wO2H   = takeB(128 * 1024);   u16* wO2L   = takeB(128 * 1024);
  u16* wL2H   = takeB(128 * 1024);   u16* wL2L   = takeB(128 * 1024);
  u16* aXh = takeB((size_t)B * 1024); u16* aXl = takeB((size_t)B * 1024);
  u16* aHh = takeB((size_t)B * 2048); u16* aHl = takeB((size_t)B * 2048);
  u16* aZh = takeB((size_t)B * 256);  u16* aZl = takeB((size_t)B * 256);
  u16* aTh = takeB((size_t)B * 2048); u16* aTl = takeB((size_t)B * 2048);
  float* logitsO = takeF((size_t)B * 65);
  float* logitsL = takeF((size_t)B * 90);
  float* nsc = takeF((size_t)B * 10);
  float* esc = takeF((size_t)B * 55);
  float* bn1sc = takeF(2048); float* bn1sh = takeF(2048);
  float* bn2sc = takeF(2048); float* bn2sh = takeF(2048);
  float* bias_mulv = takeF(512);
  float* bias_o1 = takeF(1024);
  float* bias_l1 = takeF(1024);
  float* bias_o2 = takeF(65);
  float* bias_l2 = takeF(90);

  // ---- prep: BN fold + bias concats ----
  bn_prep<<<8, 256, 0, stream>>>(bn1_g, bn1_b, bn1_m, bn1_v, bn1sc, bn1sh, 2048);
  bn_prep<<<8, 256, 0, stream>>>(bn2_g, bn2_b, bn2_m, bn2_v, bn2sc, bn2sh, 2048);
  hipMemcpyAsync(bias_mulv,        mu_b, 256 * 4, hipMemcpyDeviceToDevice, stream);
  hipMemcpyAsync(bias_mulv + 256,  lv_b, 256 * 4, hipMemcpyDeviceToDevice, stream);
  hipMemcpyAsync(bias_o1,          on_b1, 512 * 4, hipMemcpyDeviceToDevice, stream);
  hipMemcpyAsync(bias_o1 + 512,    oe_b1, 512 * 4, hipMemcpyDeviceToDevice, stream);
  hipMemcpyAsync(bias_l1,          ln_b1, 512 * 4, hipMemcpyDeviceToDevice, stream);
  hipMemcpyAsync(bias_l1 + 512,    le_b1, 512 * 4, hipMemcpyDeviceToDevice, stream);
  hipMemcpyAsync(bias_o2,          on_b2, 10 * 4, hipMemcpyDeviceToDevice, stream);
  hipMemcpyAsync(bias_o2 + 10,     oe_b2, 55 * 4, hipMemcpyDeviceToDevice, stream);
  hipMemcpyAsync(bias_l2,          ln_b2, 12 * 4, hipMemcpyDeviceToDevice, stream);
  hipMemcpyAsync(bias_l2 + 12,     le_b2, 78 * 4, hipMemcpyDeviceToDevice, stream);

  // ---- weight transpose + hi/lo conversion ----
  dim3 tb(32, 8);
  conv_wT<<<dim3(1024 / 32, 2048 / 32), tb, 0, stream>>>(enc_W, wEncH, wEncL, 1024, 2048);
  conv_wT<<<dim3(2048 / 32, 256 / 32), tb, 0, stream>>>(mu_W, wMulvH, wMulvL, 2048, 256);
  conv_wT<<<dim3(2048 / 32, 256 / 32), tb, 0, stream>>>(
      lv_W, wMulvH + (size_t)256 * 2048, wMulvL + (size_t)256 * 2048, 2048, 256);
  conv_wT<<<dim3(256 / 32, 2048 / 32), tb, 0, stream>>>(dec_W1, wDec1H, wDec1L, 256, 2048);
  conv_wT<<<dim3(2048 / 32, 2944 / 32), tb, 0, stream>>>(dec_W2, wDec2H, wDec2L, 2048, 2820);
  conv_wT<<<dim3(1024 / 32, 512 / 32), tb, 0, stream>>>(on_W1, wO1H, wO1L, 1024, 512);
  conv_wT<<<dim3(1024 / 32, 512 / 32), tb, 0, stream>>>(
      oe_W1, wO1H + (size_t)512 * 1024, wO1L + (size_t)512 * 1024, 1024, 512);
  conv_wT<<<dim3(1024 / 32, 512 / 32), tb, 0, stream>>>(ln_W1, wL1H, wL1L, 1024, 512);
  conv_wT<<<dim3(1024 / 32, 512 / 32), tb, 0, stream>>>(
      le_W1, wL1H + (size_t)512 * 1024, wL1L + (size_t)512 * 1024, 1024, 512);
  conv_w2bd<<<512, 256, 0, stream>>>(on_W2, 10, oe_W2, 55, wO2H, wO2L);
  conv_w2bd<<<512, 256, 0, stream>>>(ln_W2, 12, le_W2, 78, wL2H, wL2L);

  EpParams p;

  // ---- encode: h1 = BN(ReLU(x @ enc_W + enc_b)) ----
  conv_act<<<8192, 256, 0, stream>>>(x, aXh, aXl, B * 1024 / 4);
  p = EpParams{};
  p.bias = enc_b; p.bnsc = bn1sc; p.bnsh = bn1sh;
  p.dhi = aHh; p.dlo = aHl; p.dstride = 2048;
  gemm_k<0><<<dim3(64, 16), 256, 0, stream>>>(aXh, aXl, 1024, wEncH, wEncL, 1024, 2048, p);

  // ---- mu | logvar (concat N=512); mu also -> z hi/lo ----
  p = EpParams{};
  p.bias = bias_mulv; p.f32a = out_mu; p.f32b = out_lv;
  p.dhi = aZh; p.dlo = aZl; p.dstride = 256;
  gemm_k<1><<<dim3(64, 4), 256, 0, stream>>>(aHh, aHl, 2048, wMulvH, wMulvL, 2048, 512, p);

  // ---- decode1: h2 = BN(ReLU(z @ dec_W1 + dec_b1)) (h2 overwrites h1 buf) ----
  p = EpParams{};
  p.bias = dec_b1; p.bnsc = bn2sc; p.bnsh = bn2sh;
  p.dhi = aHh; p.dlo = aHl; p.dstride = 2048;
  gemm_k<0><<<dim3(64, 16), 256, 0, stream>>>(aZh, aZl, 256, wDec1H, wDec1L, 256, 2048, p);

  // ---- attention L1: tanh(optical@[on_W1|oe_W1]+b), tanh(log@[ln|le]+b) ----
  conv_act<<<8192, 256, 0, stream>>>(optical, aXh, aXl, B * 1024 / 4);
  p = EpParams{};
  p.bias = bias_o1; p.dhi = aTh; p.dlo = aTl; p.dstride = 2048;
  gemm_k<2><<<dim3(64, 8), 256, 0, stream>>>(aXh, aXl, 1024, wO1H, wO1L, 1024, 1024, p);
  conv_act<<<8192, 256, 0, stream>>>(logx, aXh, aXl, B * 1024 / 4);
  p.bias = bias_l1; p.dhi = aTh + 1024; p.dlo = aTl + 1024;
  gemm_k<2><<<dim3(64, 8), 256, 0, stream>>>(aXh, aXl, 1024, wL1H, wL1L, 1024, 1024, p);

  // ---- attention L2 (block-diag B): logits ----
  p = EpParams{};
  p.bias = bias_o2; p.f32a = logitsO; p.f32stride = 65;
  gemm_k<3><<<dim3(64, 1), 256, 0, stream>>>(aTh, aTl, 2048, wO2H, wO2L, 1024, 65, p);
  p.bias = bias_l2; p.f32a = logitsL; p.f32stride = 90;
  gemm_k<3><<<dim3(64, 1), 256, 0, stream>>>(aTh + 1024, aTl + 1024, 2048, wL2H, wL2L, 1024, 90, p);

  // ---- double softmax -> combined scales ----
  softmax_combine<<<32, 256, 0, stream>>>(logitsO, logitsL, nsc, esc);

  // ---- decode2 + fused attention scaling -> edge/node outputs ----
  p = EpParams{};
  p.bias = dec_b2; p.nscale = nsc; p.escale = esc;
  p.f32a = out_edge; p.f32b = out_node;
  gemm_k<4><<<dim3(64, 23), 256, 0, stream>>>(aHh, aHl, 2048, wDec2H, wDec2L, 2048, 2820, p);
}

// Round 3
// 861.844 us; speedup vs baseline: 1.3970x; 1.3970x over previous
//
#include <hip/hip_runtime.h>

using u16 = unsigned short;
using u32 = unsigned int;

typedef __attribute__((ext_vector_type(8))) short bf16x8;
typedef __attribute__((ext_vector_type(4))) float f32x4;

// ---------- fp32 <-> bf16 hi/lo split helpers ----------
__device__ __forceinline__ u16 f2bf(float f) {
  u32 u = __float_as_uint(f);
  u += 0x7fffu + ((u >> 16) & 1u);   // RNE
  return (u16)(u >> 16);
}
__device__ __forceinline__ float bf2f(u16 h) { return __uint_as_float(((u32)h) << 16); }

// async global->LDS, 16B per lane; LDS dest is wave-uniform base + lane*16
__device__ __forceinline__ void gld16(const u16* g, u16* s) {
  __builtin_amdgcn_global_load_lds((const __attribute__((address_space(1))) u32*)g,
                                   (__attribute__((address_space(3))) u32*)s, 16, 0, 0);
}

struct EpParams {
  const float* bias;
  const float* bnsc;
  const float* bnsh;
  u16* dhi; u16* dlo; int dstride;
  float* f32a; float* f32b; int f32stride;
  const float* nscale; const float* escale;
};

// ---------------------------------------------------------------------------
// Split-bf16 MFMA GEMM: C[M,N] = A[M,K] * B[K,N] (+ epilogue)
// A row-major [M,K] hi(/lo); B TRANSPOSED [Npad,K] hi(/lo), zero-padded.
// 128x128 tile, BK=32, 4 waves (2x2), each wave 64x64 = 4x4 frags of 16x16.
// NM: 1 = A_h*B_h ; 2 = + A_l*B_h ; 3 = + A_h*B_l
// LDS XOR-swizzle ((row&7)<<4 on byte addr) kills the 8-way quarter-phase
// conflict on ds_read_b128; writer stays linear (global_load_lds), source
// address inverse-swizzled per-lane (rule #21 / m173 pattern).
// EP: 0=BN(ReLU) (+SLO: hilo store)  1=mu/lv  2=tanh bf16  3=fp32 logits
//     4=dec2 + fused attention scaling
// ---------------------------------------------------------------------------
template<int EP, int NM, bool SLO>
__global__ __launch_bounds__(256, (NM == 1) ? 3 : 2) void gemm_k(
    const u16* __restrict__ Ah, const u16* __restrict__ Al, int lda,
    const u16* __restrict__ Bh, const u16* __restrict__ Bl,
    int K, int N, EpParams p)
{
  __shared__ __align__(16) u16 sAh[4096], sBh[4096];
  __shared__ __align__(16) u16 sAl[(NM >= 2) ? 4096 : 16];
  __shared__ __align__(16) u16 sBl[(NM == 3) ? 4096 : 16];
  const int t = threadIdx.x;
  const int lane = t & 63, wid = t >> 6;
  const int tm = blockIdx.x, tn = blockIdx.y;

  // staging: physical LDS slot = linear t*16B; fetch the logical (row,slot)
  // that the swizzled reader expects there. phys = logical ^ ((row&7)<<4).
  const int rp = t >> 2, sp = t & 3;
  const int rl = (rp & ~1) | ((rp & 1) ^ ((rp >> 2) & 1));
  const int sl = sp ^ (rl & 3);
  const u16* pAh = Ah + (size_t)(tm * 128 + rl) * (size_t)lda + sl * 8;
  const u16* pBh = Bh + (size_t)(tn * 128 + rl) * (size_t)K + sl * 8;
  const u16* pAl = (NM >= 2) ? Al + (size_t)(tm * 128 + rl) * (size_t)lda + sl * 8 : pAh;
  const u16* pBl = (NM == 3) ? Bl + (size_t)(tn * 128 + rl) * (size_t)K + sl * 8 : pBh;
  const size_t aStep = (size_t)64 * (size_t)lda;
  const size_t bStep = (size_t)64 * (size_t)K;

  f32x4 acc[4][4];
#pragma unroll
  for (int m = 0; m < 4; m++)
#pragma unroll
    for (int n = 0; n < 4; n++) acc[m][n] = f32x4{0.f, 0.f, 0.f, 0.f};

  const int fr = lane & 15, fg = lane >> 4;
  const int wm = wid >> 1, wn = wid & 1;

  for (int kk = 0; kk < K; kk += 32) {
    gld16(pAh + kk,          sAh + wid * 512);
    gld16(pAh + aStep + kk,  sAh + 2048 + wid * 512);
    gld16(pBh + kk,          sBh + wid * 512);
    gld16(pBh + bStep + kk,  sBh + 2048 + wid * 512);
    if constexpr (NM >= 2) {
      gld16(pAl + kk,         sAl + wid * 512);
      gld16(pAl + aStep + kk, sAl + 2048 + wid * 512);
    }
    if constexpr (NM == 3) {
      gld16(pBl + kk,         sBl + wid * 512);
      gld16(pBl + bStep + kk, sBl + 2048 + wid * 512);
    }
    __syncthreads();

    bf16x8 a_h[4], b_h[4], a_l[4], b_l[4];
#pragma unroll
    for (int f = 0; f < 4; f++) {
      const int ar = wm * 64 + f * 16 + fr;
      const int br = wn * 64 + f * 16 + fr;
      a_h[f] = *(const bf16x8*)&sAh[(ar * 32 + fg * 8) ^ ((ar & 7) << 3)];
      b_h[f] = *(const bf16x8*)&sBh[(br * 32 + fg * 8) ^ ((br & 7) << 3)];
      if constexpr (NM >= 2) a_l[f] = *(const bf16x8*)&sAl[(ar * 32 + fg * 8) ^ ((ar & 7) << 3)];
      if constexpr (NM == 3) b_l[f] = *(const bf16x8*)&sBl[(br * 32 + fg * 8) ^ ((br & 7) << 3)];
    }
#pragma unroll
    for (int m = 0; m < 4; m++)
#pragma unroll
      for (int n = 0; n < 4; n++) {
        if constexpr (NM == 3)
          acc[m][n] = __builtin_amdgcn_mfma_f32_16x16x32_bf16(a_h[m], b_l[n], acc[m][n], 0, 0, 0);
        if constexpr (NM >= 2)
          acc[m][n] = __builtin_amdgcn_mfma_f32_16x16x32_bf16(a_l[m], b_h[n], acc[m][n], 0, 0, 0);
        acc[m][n] = __builtin_amdgcn_mfma_f32_16x16x32_bf16(a_h[m], b_h[n], acc[m][n], 0, 0, 0);
      }
    __syncthreads();
  }

  // epilogue: C/D layout col=lane&15, row=4*(lane>>4)+reg  [m89-verified]
  const int rowb = tm * 128 + wm * 64;
  const int colb = tn * 128 + wn * 64;
#pragma unroll
  for (int n = 0; n < 4; n++) {
    const int col = colb + n * 16 + fr;
#pragma unroll
    for (int m = 0; m < 4; m++) {
#pragma unroll
      for (int r = 0; r < 4; r++) {
        const int row = rowb + m * 16 + fg * 4 + r;
        float val = acc[m][n][r];
        if constexpr (EP == 0) {          // bias -> relu -> bn -> store
          val += p.bias[col];
          val = fmaxf(val, 0.f);
          val = val * p.bnsc[col] + p.bnsh[col];
          u16 h = f2bf(val);
          p.dhi[(size_t)row * p.dstride + col] = h;
          if constexpr (SLO)
            p.dlo[(size_t)row * p.dstride + col] = f2bf(val - bf2f(h));
        } else if constexpr (EP == 1) {   // mu (fp32 + hilo z) | logvar (fp32)
          val += p.bias[col];
          if (col < 256) {
            p.f32a[(size_t)row * 256 + col] = val;
            u16 h = f2bf(val);
            p.dhi[(size_t)row * 256 + col] = h;
            p.dlo[(size_t)row * 256 + col] = f2bf(val - bf2f(h));
          } else {
            p.f32b[(size_t)row * 256 + (col - 256)] = val;
          }
        } else if constexpr (EP == 2) {   // tanh -> bf16 store
          val = tanhf(val + p.bias[col]);
          p.dhi[(size_t)row * p.dstride + col] = f2bf(val);
        } else if constexpr (EP == 3) {   // fp32 logits
          if (col < N) p.f32a[(size_t)row * p.f32stride + col] = val + p.bias[col];
        } else {                          // EP==4: dec2 -> scaled edge/node out
          if (col < N) {
            val += p.bias[col];
            if (col < 900) {
              int rr = col / 30, cc = col - rr * 30;
              float s = 1.f;
              if (rr >= 20 && cc >= 20 && rr <= cc) {
                int i0 = rr - 20, j0 = cc - 20;
                int k = i0 * 10 - ((i0 * (i0 - 1)) >> 1) + (j0 - i0);
                s = p.escale[(size_t)row * 55 + k];
              }
              p.f32a[(size_t)row * 900 + col] = val * s;
            } else {
              int tc = col - 900, rr = tc >> 6;
              float s = (rr >= 20) ? p.nscale[(size_t)row * 10 + (rr - 20)] : 1.f;
              p.f32b[(size_t)row * 1920 + tc] = val * s;
            }
          }
        }
      }
    }
  }
}

// ---------- fused input conversion: x -> hi/lo ; optical,log -> hi only ----------
__global__ void conv3(const float* __restrict__ x, const float* __restrict__ opt,
                      const float* __restrict__ lg, u16* __restrict__ xh,
                      u16* __restrict__ xl, u16* __restrict__ oh, u16* __restrict__ lh) {
  const int SEG = 8192 * 1024 / 4;
  int i = blockIdx.x * blockDim.x + threadIdx.x;
  if (i < SEG) {
    float4 v = ((const float4*)x)[i];
    ushort4 hh, ll;
    hh.x = f2bf(v.x); ll.x = f2bf(v.x - bf2f(hh.x));
    hh.y = f2bf(v.y); ll.y = f2bf(v.y - bf2f(hh.y));
    hh.z = f2bf(v.z); ll.z = f2bf(v.z - bf2f(hh.z));
    hh.w = f2bf(v.w); ll.w = f2bf(v.w - bf2f(hh.w));
    ((ushort4*)xh)[i] = hh;
    ((ushort4*)xl)[i] = ll;
  } else if (i < 2 * SEG) {
    int j = i - SEG;
    float4 v = ((const float4*)opt)[j];
    ushort4 hh;
    hh.x = f2bf(v.x); hh.y = f2bf(v.y); hh.z = f2bf(v.z); hh.w = f2bf(v.w);
    ((ushort4*)oh)[j] = hh;
  } else if (i < 3 * SEG) {
    int j = i - 2 * SEG;
    float4 v = ((const float4*)lg)[j];
    ushort4 hh;
    hh.x = f2bf(v.x); hh.y = f2bf(v.y); hh.z = f2bf(v.z); hh.w = f2bf(v.w);
    ((ushort4*)lh)[j] = hh;
  }
}

// ---------- W[K,N] fp32 -> Wt hi(/lo) [.,K] transposed, zero-pad n>=N ----------
__global__ void conv_wT(const float* __restrict__ W, u16* __restrict__ Th,
                        u16* __restrict__ Tl, int K, int N) {
  __shared__ float tile[32][33];
  int k0 = blockIdx.x * 32, n0 = blockIdx.y * 32;
  int tx = threadIdx.x, ty = threadIdx.y;
#pragma unroll
  for (int i = ty; i < 32; i += 8) {
    int n = n0 + tx;
    tile[i][tx] = (n < N) ? W[(size_t)(k0 + i) * N + n] : 0.f;
  }
  __syncthreads();
#pragma unroll
  for (int i = ty; i < 32; i += 8) {
    int n = n0 + i, k = k0 + tx;
    float v = tile[tx][i];
    u16 h = f2bf(v);
    Th[(size_t)n * K + k] = h;
    if (Tl) Tl[(size_t)n * K + k] = f2bf(v - bf2f(h));
  }
}

// ---------- block-diag [Wa(512xNa); Wb(512xNb)] -> Wt [128,1024] hi ----------
__global__ void conv_w2bd(const float* __restrict__ Wa, int Na,
                          const float* __restrict__ Wb, int Nb,
                          u16* __restrict__ Th) {
  int idx = blockIdx.x * blockDim.x + threadIdx.x;
  if (idx >= 128 * 1024) return;
  int n = idx >> 10, k = idx & 1023;
  float v = 0.f;
  if (n < Na) { if (k < 512) v = Wa[(size_t)k * Na + n]; }
  else if (n < Na + Nb) { if (k >= 512) v = Wb[(size_t)(k - 512) * Nb + (n - Na)]; }
  Th[idx] = f2bf(v);
}

// ---------- single prep kernel: BN folds + all bias concats ----------
struct PrepArgs {
  const float *bn1_g, *bn1_b, *bn1_m, *bn1_v, *bn2_g, *bn2_b, *bn2_m, *bn2_v;
  const float *mu_b, *lv_b, *on_b1, *oe_b1, *ln_b1, *le_b1, *on_b2, *oe_b2, *ln_b2, *le_b2;
  float *bn1sc, *bn1sh, *bn2sc, *bn2sh, *bias_mulv, *bias_o1, *bias_l1, *bias_o2, *bias_l2;
};
__global__ void prep_k(PrepArgs a) {
  int i = blockIdx.x * blockDim.x + threadIdx.x;
  if (i < 2048) {
    float s = a.bn1_g[i] * rsqrtf(a.bn1_v[i] + 1e-5f);
    a.bn1sc[i] = s; a.bn1sh[i] = a.bn1_b[i] - a.bn1_m[i] * s;
  } else if (i < 4096) {
    int j = i - 2048;
    float s = a.bn2_g[j] * rsqrtf(a.bn2_v[j] + 1e-5f);
    a.bn2sc[j] = s; a.bn2sh[j] = a.bn2_b[j] - a.bn2_m[j] * s;
  } else if (i < 4608) {
    int j = i - 4096; a.bias_mulv[j] = (j < 256) ? a.mu_b[j] : a.lv_b[j - 256];
  } else if (i < 5632) {
    int j = i - 4608; a.bias_o1[j] = (j < 512) ? a.on_b1[j] : a.oe_b1[j - 512];
  } else if (i < 6656) {
    int j = i - 5632; a.bias_l1[j] = (j < 512) ? a.ln_b1[j] : a.le_b1[j - 512];
  } else if (i < 6721) {
    int j = i - 6656; a.bias_o2[j] = (j < 10) ? a.on_b2[j] : a.oe_b2[j - 10];
  } else if (i < 6811) {
    int j = i - 6721; a.bias_l2[j] = (j < 12) ? a.ln_b2[j] : a.le_b2[j - 12];
  }
}

// ---------- combined double softmax -> per-batch scales ----------
__global__ void softmax_combine(const float* __restrict__ lo, const float* __restrict__ ll,
                                float* __restrict__ nsc, float* __restrict__ esc) {
  int b = blockIdx.x * blockDim.x + threadIdx.x;
  if (b >= 8192) return;
  const float* po = lo + (size_t)b * 65;
  const float* pl = ll + (size_t)b * 90;
  float mo = po[0];
  for (int i = 1; i < 10; i++) mo = fmaxf(mo, po[i]);
  float so = 0.f;
  for (int i = 0; i < 10; i++) so += expf(po[i] - mo);
  float ml = pl[0];
  for (int i = 1; i < 12; i++) ml = fmaxf(ml, pl[i]);
  float sl = 0.f;
  for (int i = 0; i < 12; i++) sl += expf(pl[i] - ml);
  float invn = 1.f / (so * sl);
  for (int i = 0; i < 10; i++)
    nsc[(size_t)b * 10 + i] = expf(po[i] - mo) * expf(pl[i] - ml) * invn;
  const float* qo = po + 10;
  const float* ql = pl + 12;
  float meo = qo[0];
  for (int i = 1; i < 55; i++) meo = fmaxf(meo, qo[i]);
  float seo = 0.f;
  for (int i = 0; i < 55; i++) seo += expf(qo[i] - meo);
  float mel = ql[0];
  for (int i = 1; i < 78; i++) mel = fmaxf(mel, ql[i]);
  float sel = 0.f;
  for (int i = 0; i < 78; i++) sel += expf(ql[i] - mel);
  float inve = 1.f / (seo * sel);
  for (int k = 0; k < 55; k++)
    esc[(size_t)b * 55 + k] = expf(qo[k] - meo) * expf(ql[k] - mel) * inve;
}

// ---------------------------------------------------------------------------
extern "C" void kernel_launch(void* const* d_in, const int* in_sizes, int n_in,
                              void* d_out, int out_size, void* d_ws, size_t ws_size,
                              hipStream_t stream) {
  const float* x       = (const float*)d_in[0];
  const float* optical = (const float*)d_in[1];
  const float* logx    = (const float*)d_in[2];
  const float* enc_W   = (const float*)d_in[3];
  const float* enc_b   = (const float*)d_in[4];
  const float* bn1_g   = (const float*)d_in[5];
  const float* bn1_b   = (const float*)d_in[6];
  const float* bn1_m   = (const float*)d_in[7];
  const float* bn1_v   = (const float*)d_in[8];
  const float* mu_W    = (const float*)d_in[9];
  const float* mu_b    = (const float*)d_in[10];
  const float* lv_W    = (const float*)d_in[11];
  const float* lv_b    = (const float*)d_in[12];
  const float* dec_W1  = (const float*)d_in[13];
  const float* dec_b1  = (const float*)d_in[14];
  const float* bn2_g   = (const float*)d_in[15];
  const float* bn2_b   = (const float*)d_in[16];
  const float* bn2_m   = (const float*)d_in[17];
  const float* bn2_v   = (const float*)d_in[18];
  const float* dec_W2  = (const float*)d_in[19];
  const float* dec_b2  = (const float*)d_in[20];
  const float* on_W1   = (const float*)d_in[21];
  const float* on_b1   = (const float*)d_in[22];
  const float* on_W2   = (const float*)d_in[23];
  const float* on_b2   = (const float*)d_in[24];
  const float* oe_W1   = (const float*)d_in[25];
  const float* oe_b1   = (const float*)d_in[26];
  const float* oe_W2   = (const float*)d_in[27];
  const float* oe_b2   = (const float*)d_in[28];
  const float* ln_W1   = (const float*)d_in[29];
  const float* ln_b1   = (const float*)d_in[30];
  const float* ln_W2   = (const float*)d_in[31];
  const float* ln_b2   = (const float*)d_in[32];
  const float* le_W1   = (const float*)d_in[33];
  const float* le_b1   = (const float*)d_in[34];
  const float* le_W2   = (const float*)d_in[35];
  const float* le_b2   = (const float*)d_in[36];

  const int B = 8192;
  float* out_edge = (float*)d_out;
  float* out_node = out_edge + (size_t)B * 900;
  float* out_mu   = out_node + (size_t)B * 1920;
  float* out_lv   = out_mu + (size_t)B * 256;

  // ---- workspace carve (~211 MB) ----
  char* base = (char*)d_ws;
  size_t off = 0;
  auto takeB = [&](size_t elems) -> u16* {
    u16* p = (u16*)(base + off);
    off = (off + elems * 2 + 255) & ~(size_t)255;
    return p;
  };
  auto takeF = [&](size_t elems) -> float* {
    float* p = (float*)(base + off);
    off = (off + elems * 4 + 255) & ~(size_t)255;
    return p;
  };
  u16* wEncH  = takeB(2048 * 1024);
  u16* wMulvH = takeB(512 * 2048);   u16* wMulvL = takeB(512 * 2048);
  u16* wDec1H = takeB(2048 * 256);   u16* wDec1L = takeB(2048 * 256);
  u16* wDec2H = takeB(2944 * 2048);
  u16* wO1H   = takeB(1024 * 1024);
  u16* wL1H   = takeB(1024 * 1024);
  u16* wO2H   = takeB(128 * 1024);
  u16* wL2H   = takeB(128 * 1024);
  u16* aXh = takeB((size_t)B * 1024); u16* aXl = takeB((size_t)B * 1024);
  u16* aOh = takeB((size_t)B * 1024);
  u16* aLh = takeB((size_t)B * 1024);
  u16* aHh = takeB((size_t)B * 2048); u16* aHl = takeB((size_t)B * 2048);
  u16* aZh = takeB((size_t)B * 256);  u16* aZl = takeB((size_t)B * 256);
  u16* aTh = takeB((size_t)B * 2048);
  float* logitsO = takeF((size_t)B * 65);
  float* logitsL = takeF((size_t)B * 90);
  float* nsc = takeF((size_t)B * 10);
  float* esc = takeF((size_t)B * 55);
  float* bn1sc = takeF(2048); float* bn1sh = takeF(2048);
  float* bn2sc = takeF(2048); float* bn2sh = takeF(2048);
  float* bias_mulv = takeF(512);
  float* bias_o1 = takeF(1024);
  float* bias_l1 = takeF(1024);
  float* bias_o2 = takeF(65);
  float* bias_l2 = takeF(90);

  // ---- prep: BN fold + bias concats, single launch ----
  PrepArgs pa;
  pa.bn1_g = bn1_g; pa.bn1_b = bn1_b; pa.bn1_m = bn1_m; pa.bn1_v = bn1_v;
  pa.bn2_g = bn2_g; pa.bn2_b = bn2_b; pa.bn2_m = bn2_m; pa.bn2_v = bn2_v;
  pa.mu_b = mu_b; pa.lv_b = lv_b;
  pa.on_b1 = on_b1; pa.oe_b1 = oe_b1; pa.ln_b1 = ln_b1; pa.le_b1 = le_b1;
  pa.on_b2 = on_b2; pa.oe_b2 = oe_b2; pa.ln_b2 = ln_b2; pa.le_b2 = le_b2;
  pa.bn1sc = bn1sc; pa.bn1sh = bn1sh; pa.bn2sc = bn2sc; pa.bn2sh = bn2sh;
  pa.bias_mulv = bias_mulv; pa.bias_o1 = bias_o1; pa.bias_l1 = bias_l1;
  pa.bias_o2 = bias_o2; pa.bias_l2 = bias_l2;
  prep_k<<<27, 256, 0, stream>>>(pa);

  // ---- input conversions, single launch ----
  conv3<<<24576, 256, 0, stream>>>(x, optical, logx, aXh, aXl, aOh, aLh);

  // ---- weight transpose + conversion ----
  dim3 tb(32, 8);
  conv_wT<<<dim3(32, 64), tb, 0, stream>>>(enc_W, wEncH, nullptr, 1024, 2048);
  conv_wT<<<dim3(64, 8), tb, 0, stream>>>(mu_W, wMulvH, wMulvL, 2048, 256);
  conv_wT<<<dim3(64, 8), tb, 0, stream>>>(
      lv_W, wMulvH + (size_t)256 * 2048, wMulvL + (size_t)256 * 2048, 2048, 256);
  conv_wT<<<dim3(8, 64), tb, 0, stream>>>(dec_W1, wDec1H, wDec1L, 256, 2048);
  conv_wT<<<dim3(64, 92), tb, 0, stream>>>(dec_W2, wDec2H, nullptr, 2048, 2820);
  conv_wT<<<dim3(32, 16), tb, 0, stream>>>(on_W1, wO1H, nullptr, 1024, 512);
  conv_wT<<<dim3(32, 16), tb, 0, stream>>>(oe_W1, wO1H + (size_t)512 * 1024, nullptr, 1024, 512);
  conv_wT<<<dim3(32, 16), tb, 0, stream>>>(ln_W1, wL1H, nullptr, 1024, 512);
  conv_wT<<<dim3(32, 16), tb, 0, stream>>>(le_W1, wL1H + (size_t)512 * 1024, nullptr, 1024, 512);
  conv_w2bd<<<512, 256, 0, stream>>>(on_W2, 10, oe_W2, 55, wO2H);
  conv_w2bd<<<512, 256, 0, stream>>>(ln_W2, 12, le_W2, 78, wL2H);

  EpParams p;

  // ---- encode: h1 = BN(ReLU(x @ enc_W + enc_b))  [NM=2: hh + lh] ----
  p = EpParams{};
  p.bias = enc_b; p.bnsc = bn1sc; p.bnsh = bn1sh;
  p.dhi = aHh; p.dlo = aHl; p.dstride = 2048;
  gemm_k<0, 2, true><<<dim3(64, 16), 256, 0, stream>>>(
      aXh, aXl, 1024, wEncH, nullptr, 1024, 2048, p);

  // ---- mu | logvar (concat N=512) [NM=3]; mu also -> z hi/lo ----
  p = EpParams{};
  p.bias = bias_mulv; p.f32a = out_mu; p.f32b = out_lv;
  p.dhi = aZh; p.dlo = aZl; p.dstride = 256;
  gemm_k<1, 3, false><<<dim3(64, 4), 256, 0, stream>>>(
      aHh, aHl, 2048, wMulvH, wMulvL, 2048, 512, p);

  // ---- decode1: h2 = BN(ReLU(z @ dec_W1 + dec_b1)) [NM=3, hi-only store] ----
  p = EpParams{};
  p.bias = dec_b1; p.bnsc = bn2sc; p.bnsh = bn2sh;
  p.dhi = aHh; p.dlo = nullptr; p.dstride = 2048;
  gemm_k<0, 3, false><<<dim3(64, 16), 256, 0, stream>>>(
      aZh, aZl, 256, wDec1H, wDec1L, 256, 2048, p);

  // ---- attention L1: tanh(...) [NM=1, plain bf16] ----
  p = EpParams{};
  p.bias = bias_o1; p.dhi = aTh; p.dstride = 2048;
  gemm_k<2, 1, false><<<dim3(64, 8), 256, 0, stream>>>(
      aOh, nullptr, 1024, wO1H, nullptr, 1024, 1024, p);
  p.bias = bias_l1; p.dhi = aTh + 1024;
  gemm_k<2, 1, false><<<dim3(64, 8), 256, 0, stream>>>(
      aLh, nullptr, 1024, wL1H, nullptr, 1024, 1024, p);

  // ---- attention L2 (block-diag B): logits [NM=1] ----
  p = EpParams{};
  p.bias = bias_o2; p.f32a = logitsO; p.f32stride = 65;
  gemm_k<3, 1, false><<<dim3(64, 1), 256, 0, stream>>>(
      aTh, nullptr, 2048, wO2H, nullptr, 1024, 65, p);
  p.bias = bias_l2; p.f32a = logitsL; p.f32stride = 90;
  gemm_k<3, 1, false><<<dim3(64, 1), 256, 0, stream>>>(
      aTh + 1024, nullptr, 2048, wL2H, nullptr, 1024, 90, p);

  // ---- double softmax -> combined scales ----
  softmax_combine<<<32, 256, 0, stream>>>(logitsO, logitsL, nsc, esc);

  // ---- decode2 + fused attention scaling [NM=1, plain bf16] ----
  p = EpParams{};
  p.bias = dec_b2; p.nscale = nsc; p.escale = esc;
  p.f32a = out_edge; p.f32b = out_node;
  gemm_k<4, 1, false><<<dim3(64, 23), 256, 0, stream>>>(
      aHh, nullptr, 2048, wDec2H, nullptr, 2048, 2820, p);
}